// Round 10
// baseline (21.544 us; speedup 1.0000x reference)
//
#include <hip/hip_runtime.h>
#include <hip/hip_bf16.h>

#define B_   16
#define NC_  1024
#define NQ_  128
#define D_   512
#define BM   16
#define BK   64
#define NKT  8        // K-tiles: 512/64

typedef __attribute__((ext_vector_type(8))) short bf16x8;
typedef __attribute__((ext_vector_type(4))) float f32x4;
typedef __attribute__((address_space(3))) char lds_char;
typedef const __attribute__((address_space(1))) char g_char;

// fp32 -> bf16 RTNE
__device__ __forceinline__ short f2bf(float x) {
    return __builtin_bit_cast(short, __float2bfloat16(x));
}

// Pre-kernel: qw[b][j][d] = bf16(q*w_cq + w_c); qterm[b][j] = q . w_q
__global__ __launch_bounds__(256) void prep_kernel(
    const float* __restrict__ q, const float* __restrict__ kern,
    short* __restrict__ qw, float* __restrict__ qterm)
{
    const int tid  = threadIdx.x;
    const int lane = tid & 63;
    const int row  = blockIdx.x * 4 + (tid >> 6);   // 0..2047 (b*128 + j)
    const int k0   = lane * 8;
    const float* qr = q + (size_t)row * D_;
    f32x4 a0 = *(const f32x4*)(qr + k0);
    f32x4 a1 = *(const f32x4*)(qr + k0 + 4);
    f32x4 g0 = *(const f32x4*)(kern + 2 * D_ + k0);      // w_cq
    f32x4 g1 = *(const f32x4*)(kern + 2 * D_ + k0 + 4);
    f32x4 w0 = *(const f32x4*)(kern + D_ + k0);          // w_q
    f32x4 w1 = *(const f32x4*)(kern + D_ + k0 + 4);
    f32x4 h0 = *(const f32x4*)(kern + k0);               // w_c
    f32x4 h1 = *(const f32x4*)(kern + k0 + 4);
    bf16x8 o;
    o[0] = f2bf(a0[0] * g0[0] + h0[0]); o[1] = f2bf(a0[1] * g0[1] + h0[1]);
    o[2] = f2bf(a0[2] * g0[2] + h0[2]); o[3] = f2bf(a0[3] * g0[3] + h0[3]);
    o[4] = f2bf(a1[0] * g1[0] + h1[0]); o[5] = f2bf(a1[1] * g1[1] + h1[1]);
    o[6] = f2bf(a1[2] * g1[2] + h1[2]); o[7] = f2bf(a1[3] * g1[3] + h1[3]);
    *(bf16x8*)(qw + (size_t)row * D_ + k0) = o;
    float s = a0[0]*w0[0] + a0[1]*w0[1] + a0[2]*w0[2] + a0[3]*w0[3]
            + a1[0]*w1[0] + a1[1]*w1[1] + a1[2]*w1[2] + a1[3]*w1[3];
    s += __shfl_xor(s, 1);  s += __shfl_xor(s, 2);  s += __shfl_xor(s, 4);
    s += __shfl_xor(s, 8);  s += __shfl_xor(s, 16); s += __shfl_xor(s, 32);
    if (lane == 0) qterm[row] = s;
}

// Main GEMM: out[b][i][j] = (c[b][i] . qw[b][j]) + qterm[b][j] + bias
// R10: T3+T4 proper. Ring-3 LDS buffers (3x20KB=60KB, 2 blocks/CU), stage-ahead-2,
// RAW s_barrier (no implicit vmcnt(0) drain — __syncthreads would add one!) +
// counted s_waitcnt vmcnt(5): kt+1's 5 loads (issued a phase earlier) are waited,
// kt+2's 5 remain in flight across the barrier. Everything else verbatim R9.
__global__ __launch_bounds__(256, 2) void sim_kernel(
    const float* __restrict__ c, const short* __restrict__ qw,
    const float* __restrict__ qterm, const float* __restrict__ bias_p,
    float* __restrict__ out)
{
    __shared__ char lds[3][20480];

    const int bid  = blockIdx.x;
    const int b    = ((bid & 7) << 1) | (bid >> 9);  // XCD-affine batch (bijective)
    const int mt   = (bid >> 3) & 63;                // 64 M-tiles per batch
    const int tid  = threadIdx.x;
    const int lane = tid & 63;
    const int w    = tid >> 6;          // wave 0..3 -> N columns w*32..w*32+31
    const int rif  = lane & 15;
    const int kg   = lane >> 4;

    // --- staging source addresses (per lane), k-tile 0 ---
    // A: 4KB = 4 wave-chunks of 1KB (ch = w); row = ch*4 + lane>>4 (256B rows)
    const char* asrc; int adst;
    {
        int r = w * 4 + (lane >> 4);
        int so = ((lane & 15) * 16) ^ ((r & 7) << 4);
        asrc = (const char*)c + ((size_t)(b * NC_ + mt * BM + r) * D_) * 4 + so;
        adst = w * 1024 + lane * 16;
    }
    // B: 16KB = 16 wave-chunks; ch = w*4+l covers j-rows ch*8..+7 (128B rows)
    const char* bsrc[4]; int bdst[4];
    #pragma unroll
    for (int l = 0; l < 4; ++l) {
        int ch = w * 4 + l;
        int j  = ch * 8 + (lane >> 3);
        int so = ((lane & 7) * 16) ^ ((j & 7) << 4);
        bsrc[l] = (const char*)qw + ((size_t)(b * NQ_ + j) * D_) * 2 + so;
        bdst[l] = 4096 + ch * 1024 + lane * 16;
    }

#define STAGE(BUF, KT)                                                            \
    do {                                                                          \
        lds_char* L_ = (lds_char*)&lds[(BUF)][0];                                 \
        __builtin_amdgcn_global_load_lds((g_char*)(asrc + (KT) * 256),            \
                                         (lds_char*)(L_ + adst), 16, 0, 0);       \
        __builtin_amdgcn_global_load_lds((g_char*)(bsrc[0] + (KT) * 128),         \
                                         (lds_char*)(L_ + bdst[0]), 16, 0, 0);    \
        __builtin_amdgcn_global_load_lds((g_char*)(bsrc[1] + (KT) * 128),         \
                                         (lds_char*)(L_ + bdst[1]), 16, 0, 0);    \
        __builtin_amdgcn_global_load_lds((g_char*)(bsrc[2] + (KT) * 128),         \
                                         (lds_char*)(L_ + bdst[2]), 16, 0, 0);    \
        __builtin_amdgcn_global_load_lds((g_char*)(bsrc[3] + (KT) * 128),         \
                                         (lds_char*)(L_ + bdst[3]), 16, 0, 0);    \
    } while (0)

    f32x4 acc[2] = {};

    // Prologue: stage kt0 and kt1 (10 loads in flight); wait kt0's 5 only.
    STAGE(0, 0);
    STAGE(1, 1);
    asm volatile("s_waitcnt vmcnt(5)" ::: "memory");
    __builtin_amdgcn_s_barrier();
    __builtin_amdgcn_sched_barrier(0);

    #pragma unroll 1
    for (int kt = 0; kt < NKT; ++kt) {
        const int cb = kt % 3;
        if (kt + 2 < NKT) STAGE((kt + 2) % 3, kt + 2);   // issue ahead-2 first

        const char* L = &lds[cb][0];
        #pragma unroll
        for (int kk = 0; kk < 2; ++kk) {
            bf16x8 af;
            {
                int sw = (rif & 7) << 4;
                f32x4 v0 = *(const f32x4*)(L + rif * 256 + ((kk * 128 + kg * 32 +  0) ^ sw));
                f32x4 v1 = *(const f32x4*)(L + rif * 256 + ((kk * 128 + kg * 32 + 16) ^ sw));
                af[0] = f2bf(v0[0]); af[1] = f2bf(v0[1]); af[2] = f2bf(v0[2]); af[3] = f2bf(v0[3]);
                af[4] = f2bf(v1[0]); af[5] = f2bf(v1[1]); af[6] = f2bf(v1[2]); af[7] = f2bf(v1[3]);
            }
            #pragma unroll
            for (int nf = 0; nf < 2; ++nf) {
                int j = w * 32 + nf * 16 + rif;
                bf16x8 bfr = *(const bf16x8*)(L + 4096 + j * 128
                                              + ((kk * 64 + kg * 16) ^ ((j & 7) << 4)));
                acc[nf] = __builtin_amdgcn_mfma_f32_16x16x32_bf16(af, bfr, acc[nf], 0, 0, 0);
            }
        }

        // Wait only kt+1's loads (issued last iter); kt+2's stay in flight.
        if (kt + 2 < NKT) {
            asm volatile("s_waitcnt vmcnt(5)" ::: "memory");
        } else if (kt + 1 < NKT) {
            asm volatile("s_waitcnt vmcnt(0)" ::: "memory");
        }
        if (kt + 1 < NKT) {
            __builtin_amdgcn_s_barrier();
            __builtin_amdgcn_sched_barrier(0);
        }
    }
#undef STAGE

    const float bias = *bias_p;
    #pragma unroll
    for (int nf = 0; nf < 2; ++nf) {
        const float qt = qterm[b * NQ_ + w * 32 + nf * 16 + rif] + bias;
        float* o = out + ((size_t)(b * NC_ + mt * BM + kg * 4)) * NQ_
                 + w * 32 + nf * 16 + rif;
        #pragma unroll
        for (int r = 0; r < 4; ++r)
            o[(size_t)r * NQ_] = acc[nf][r] + qt;
    }
}

extern "C" void kernel_launch(void* const* d_in, const int* in_sizes, int n_in,
                              void* d_out, int out_size, void* d_ws, size_t ws_size,
                              hipStream_t stream) {
    const float* c    = (const float*)d_in[0];
    const float* q    = (const float*)d_in[1];
    const float* kern = (const float*)d_in[2];
    const float* bias = (const float*)d_in[3];
    float* out = (float*)d_out;

    // ws layout: qw bf16 [2048][512] (2 MiB) | qterm f32 [2048]
    short* qw    = (short*)d_ws;
    float* qterm = (float*)((char*)d_ws + (size_t)2048 * 512 * 2);

    prep_kernel<<<512, 256, 0, stream>>>(q, kern, qw, qterm);
    sim_kernel<<<1024, 256, 0, stream>>>(c, qw, qterm, bias, out);
}

// Round 11
// 19.203 us; speedup vs baseline: 1.1219x; 1.1219x over previous
//
#include <hip/hip_runtime.h>
#include <hip/hip_bf16.h>

#define B_   16
#define NC_  1024
#define NQ_  128
#define D_   512
#define NKT  8        // K-tiles: 512/64

typedef __attribute__((ext_vector_type(8))) short bf16x8;
typedef __attribute__((ext_vector_type(4))) float f32x4;
typedef __attribute__((address_space(3))) char lds_char;
typedef const __attribute__((address_space(1))) char g_char;

// fp32 -> bf16 RTNE
__device__ __forceinline__ short f2bf(float x) {
    return __builtin_bit_cast(short, __float2bfloat16(x));
}

// Pre-kernel: qw[b][j][d] = bf16(q*w_cq + w_c); qterm[b][j] = q . w_q
__global__ __launch_bounds__(256) void prep_kernel(
    const float* __restrict__ q, const float* __restrict__ kern,
    short* __restrict__ qw, float* __restrict__ qterm)
{
    const int tid  = threadIdx.x;
    const int lane = tid & 63;
    const int row  = blockIdx.x * 4 + (tid >> 6);   // 0..2047 (b*128 + j)
    const int k0   = lane * 8;
    const float* qr = q + (size_t)row * D_;
    f32x4 a0 = *(const f32x4*)(qr + k0);
    f32x4 a1 = *(const f32x4*)(qr + k0 + 4);
    f32x4 g0 = *(const f32x4*)(kern + 2 * D_ + k0);      // w_cq
    f32x4 g1 = *(const f32x4*)(kern + 2 * D_ + k0 + 4);
    f32x4 w0 = *(const f32x4*)(kern + D_ + k0);          // w_q
    f32x4 w1 = *(const f32x4*)(kern + D_ + k0 + 4);
    f32x4 h0 = *(const f32x4*)(kern + k0);               // w_c
    f32x4 h1 = *(const f32x4*)(kern + k0 + 4);
    bf16x8 o;
    o[0] = f2bf(a0[0] * g0[0] + h0[0]); o[1] = f2bf(a0[1] * g0[1] + h0[1]);
    o[2] = f2bf(a0[2] * g0[2] + h0[2]); o[3] = f2bf(a0[3] * g0[3] + h0[3]);
    o[4] = f2bf(a1[0] * g1[0] + h1[0]); o[5] = f2bf(a1[1] * g1[1] + h1[1]);
    o[6] = f2bf(a1[2] * g1[2] + h1[2]); o[7] = f2bf(a1[3] * g1[3] + h1[3]);
    *(bf16x8*)(qw + (size_t)row * D_ + k0) = o;
    float s = a0[0]*w0[0] + a0[1]*w0[1] + a0[2]*w0[2] + a0[3]*w0[3]
            + a1[0]*w1[0] + a1[1]*w1[1] + a1[2]*w1[2] + a1[3]*w1[3];
    s += __shfl_xor(s, 1);  s += __shfl_xor(s, 2);  s += __shfl_xor(s, 4);
    s += __shfl_xor(s, 8);  s += __shfl_xor(s, 16); s += __shfl_xor(s, 32);
    if (lane == 0) qterm[row] = s;
}

// R11: LDS-byte attack. Block tile 64x64, 4 waves as 2Mx2N (wave tile 32x32,
// each frag read feeds 2 MFMAs). A stored BF16 in LDS via reg-staging
// (global fp32 -> cvt_pk -> ds_write_b128, XOR-swizzled layout); B via
// global_load_lds (pre-swizzled source, verbatim R9 scheme on 64 rows).
// Ring-3 LDS bufs (3x16KB=48KB, 3 blocks/CU); stage kt+1 at kt-top,
// sched_barrier(0) pins the issue-early block; one __syncthreads per kt
// (its implicit vmcnt(0) drain is required anyway: A+B of kt+1 must be
// complete at the barrier). Per-CU LDS traffic: 1.7MB -> 0.77MB.
__global__ __launch_bounds__(256, 3) void sim_kernel(
    const float* __restrict__ c, const short* __restrict__ qw,
    const float* __restrict__ qterm, const float* __restrict__ bias_p,
    float* __restrict__ out)
{
    __shared__ char lds[3][16384];   // per buf: A bf16 [64][64] (8KB) | B bf16 [64][64] (8KB)

    const int bid   = blockIdx.x;
    const int b     = ((bid & 7) << 1) | (bid >> 8);   // XCD-affine batch (bijective, 512 blocks)
    const int inner = (bid >> 3) & 31;
    const int mt    = inner >> 1;                      // 16 M-tiles of 64 rows
    const int nb    = inner & 1;                       // 2 N-halves of 64 cols
    const int tid   = threadIdx.x;
    const int lane  = tid & 63;
    const int w     = tid >> 6;
    const int wm    = w >> 1, wn = w & 1;              // 2x2 wave grid
    const int rif   = lane & 15;
    const int kg    = lane >> 4;

    // --- A reg-staging: thread t loads rows r0=t>>3, r1=r0+32; 8 floats at col (t&7)*8 ---
    const float* ag0 = c + (size_t)(b * NC_ + mt * 64 + (tid >> 3)) * D_ + (tid & 7) * 8;
    const float* ag1 = ag0 + (size_t)32 * D_;
    const int ar0 = tid >> 3, ar1 = ar0 + 32;
    const int aw0 = ar0 * 128 + (((tid & 7) * 16) ^ ((ar0 & 7) << 4));
    const int aw1 = ar1 * 128 + (((tid & 7) * 16) ^ ((ar1 & 7) << 4));

    // --- B staging via gload_lds: ch = w*2+l covers j-rows ch*8..+7 (128B rows) ---
    const char* bsrc[2]; int bdst[2];
    #pragma unroll
    for (int l = 0; l < 2; ++l) {
        int ch = w * 2 + l;
        int j  = ch * 8 + (lane >> 3);
        int so = ((lane & 7) * 16) ^ ((j & 7) << 4);
        bsrc[l] = (const char*)qw + ((size_t)(b * NQ_ + nb * 64 + j) * D_) * 2 + so;
        bdst[l] = 8192 + ch * 1024 + lane * 16;
    }

#define BSTAGE(BUF, KT)                                                           \
    do {                                                                          \
        lds_char* L_ = (lds_char*)&lds[(BUF)][0];                                 \
        __builtin_amdgcn_global_load_lds((g_char*)(bsrc[0] + (KT) * 128),         \
                                         (lds_char*)(L_ + bdst[0]), 16, 0, 0);    \
        __builtin_amdgcn_global_load_lds((g_char*)(bsrc[1] + (KT) * 128),         \
                                         (lds_char*)(L_ + bdst[1]), 16, 0, 0);    \
    } while (0)

#define ACVT(O0, O1, A00, A01, A10, A11)                                          \
    do {                                                                          \
        O0[0]=f2bf(A00[0]); O0[1]=f2bf(A00[1]); O0[2]=f2bf(A00[2]); O0[3]=f2bf(A00[3]); \
        O0[4]=f2bf(A01[0]); O0[5]=f2bf(A01[1]); O0[6]=f2bf(A01[2]); O0[7]=f2bf(A01[3]); \
        O1[0]=f2bf(A10[0]); O1[1]=f2bf(A10[1]); O1[2]=f2bf(A10[2]); O1[3]=f2bf(A10[3]); \
        O1[4]=f2bf(A11[0]); O1[5]=f2bf(A11[1]); O1[6]=f2bf(A11[2]); O1[7]=f2bf(A11[3]); \
    } while (0)

    f32x4 acc00 = {}, acc01 = {}, acc10 = {}, acc11 = {};

    // Prologue: stage kt=0 into buf0
    {
        f32x4 a00 = *(const f32x4*)(ag0);
        f32x4 a01 = *(const f32x4*)(ag0 + 4);
        f32x4 a10 = *(const f32x4*)(ag1);
        f32x4 a11 = *(const f32x4*)(ag1 + 4);
        BSTAGE(0, 0);
        bf16x8 o0, o1;
        ACVT(o0, o1, a00, a01, a10, a11);
        *(bf16x8*)(&lds[0][aw0]) = o0;
        *(bf16x8*)(&lds[0][aw1]) = o1;
        __syncthreads();    // drains B gload_lds (vmcnt) + A ds_writes (lgkm)
    }

    #pragma unroll 1
    for (int kt = 0; kt < NKT; ++kt) {
        const bool st = (kt + 1 < NKT);
        f32x4 a00, a01, a10, a11;
        if (st) {   // issue kt+1 stage EARLY: A global loads + B gload_lds
            const float* g0 = ag0 + (kt + 1) * 64;
            const float* g1 = ag1 + (kt + 1) * 64;
            a00 = *(const f32x4*)(g0);
            a01 = *(const f32x4*)(g0 + 4);
            a10 = *(const f32x4*)(g1);
            a11 = *(const f32x4*)(g1 + 4);
            BSTAGE((kt + 1) % 3, kt + 1);
        }
        __builtin_amdgcn_sched_barrier(0);   // pin loads above compute (stop sinking)

        const char* L = &lds[kt % 3][0];
        #pragma unroll
        for (int kk = 0; kk < 2; ++kk) {
            const int ks = kk * 64 + kg * 16;
            bf16x8 af0, af1, bf0, bf1;
            { int r = wm * 32 + rif;      af0 = *(const bf16x8*)(L + r * 128 + (ks ^ ((r & 7) << 4))); }
            { int r = wm * 32 + 16 + rif; af1 = *(const bf16x8*)(L + r * 128 + (ks ^ ((r & 7) << 4))); }
            { int j = wn * 32 + rif;      bf0 = *(const bf16x8*)(L + 8192 + j * 128 + (ks ^ ((j & 7) << 4))); }
            { int j = wn * 32 + 16 + rif; bf1 = *(const bf16x8*)(L + 8192 + j * 128 + (ks ^ ((j & 7) << 4))); }
            acc00 = __builtin_amdgcn_mfma_f32_16x16x32_bf16(af0, bf0, acc00, 0, 0, 0);
            acc01 = __builtin_amdgcn_mfma_f32_16x16x32_bf16(af0, bf1, acc01, 0, 0, 0);
            acc10 = __builtin_amdgcn_mfma_f32_16x16x32_bf16(af1, bf0, acc10, 0, 0, 0);
            acc11 = __builtin_amdgcn_mfma_f32_16x16x32_bf16(af1, bf1, acc11, 0, 0, 0);
        }

        if (st) {   // cvt + ds_write A(kt+1) into buf[(kt+1)%3] (last read at kt-2: safe)
            char* Ln = &lds[(kt + 1) % 3][0];
            bf16x8 o0, o1;
            ACVT(o0, o1, a00, a01, a10, a11);
            *(bf16x8*)(Ln + aw0) = o0;
            *(bf16x8*)(Ln + aw1) = o1;
            __syncthreads();   // implicit vmcnt(0)+lgkm(0): A writes + B gload_lds complete
        }
    }
#undef BSTAGE
#undef ACVT

    const float bias = *bias_p;
    const int colbase = nb * 64 + wn * 32;
    const float qt0 = qterm[b * NQ_ + colbase + rif]      + bias;
    const float qt1 = qterm[b * NQ_ + colbase + 16 + rif] + bias;
    #pragma unroll
    for (int mf = 0; mf < 2; ++mf) {
        float* o = out + ((size_t)(b * NC_ + mt * 64 + wm * 32 + mf * 16 + kg * 4)) * NQ_
                 + colbase + rif;
        const f32x4 a0 = mf ? acc10 : acc00;
        const f32x4 a1 = mf ? acc11 : acc01;
        #pragma unroll
        for (int r = 0; r < 4; ++r) {
            o[(size_t)r * NQ_ +  0] = a0[r] + qt0;
            o[(size_t)r * NQ_ + 16] = a1[r] + qt1;
        }
    }
}

extern "C" void kernel_launch(void* const* d_in, const int* in_sizes, int n_in,
                              void* d_out, int out_size, void* d_ws, size_t ws_size,
                              hipStream_t stream) {
    const float* c    = (const float*)d_in[0];
    const float* q    = (const float*)d_in[1];
    const float* kern = (const float*)d_in[2];
    const float* bias = (const float*)d_in[3];
    float* out = (float*)d_out;

    // ws layout: qw bf16 [2048][512] (2 MiB) | qterm f32 [2048]
    short* qw    = (short*)d_ws;
    float* qterm = (float*)((char*)d_ws + (size_t)2048 * 512 * 2);

    prep_kernel<<<512, 256, 0, stream>>>(q, kern, qw, qterm);
    sim_kernel<<<512, 256, 0, stream>>>(c, qw, qterm, bias, out);  // 16b x 16mt x 2nb
}